// Round 4
// baseline (167.986 us; speedup 1.0000x reference)
//
#include <hip/hip_runtime.h>

typedef unsigned short u16;
typedef __attribute__((ext_vector_type(8))) short short8;
typedef __attribute__((ext_vector_type(4))) short short4v;
typedef __attribute__((ext_vector_type(4))) float f32x4;
typedef __attribute__((ext_vector_type(2))) unsigned int uint2v;

#define DEV static __device__ __forceinline__

static_assert(sizeof(short8) == 16, "short8 must be 16B");

// ---------- helpers ----------
DEV u16 f2b(float f) {                       // fp32 -> bf16, round-to-nearest-even
  union { float f; unsigned u; } a; a.f = f;
  unsigned u = a.u;
  unsigned r = (u + 0x7FFFu + ((u >> 16) & 1u)) >> 16;
  return (u16)r;
}

DEV unsigned cvt_pk_bf16(float lo, float hi) {   // {bf16(lo), bf16(hi)} packed
  unsigned r;
  asm("v_cvt_pk_bf16_f32 %0, %1, %2" : "=v"(r) : "v"(lo), "v"(hi));
  return r;
}

DEV f32x4 mfma16(short8 a, short8 b, f32x4 c) {
  asm volatile("v_mfma_f32_16x16x32_bf16 %0, %1, %2, %0" : "+v"(c) : "v"(a), "v"(b));
  return c;
}
DEV f32x4 fence_nops(f32x4 c) { asm volatile("s_nop 7\n\ts_nop 7" : "+v"(c)); return c; }
DEV f32x4 fence0(f32x4 c)     { asm volatile("" : "+v"(c)); return c; }

// async global->LDS, 16B per lane; LDS dest must be wave-uniform base + lane*16
DEV void gl_lds16(const u16* g, u16* l) {
  __builtin_amdgcn_global_load_lds(
      (const __attribute__((address_space(1))) void*)g,
      (__attribute__((address_space(3))) void*)l, 16, 0, 0);
}

// ---------- problem dims ----------
constexpr int Bz = 8, Nseq = 1024, Emb = 768, Hh = 8, Dh = 96;
constexpr int Mrows = Bz * Nseq;    // 8192
constexpr int K3 = 3 * Emb;         // 2304
// 768^-0.5 * log2(e): softmax done in exp2 domain (saves a mul per S element)
constexpr float QSCALE = 0.05205982021128899f;

// ---------- kernel 1: x fp32 -> bf16 ----------
__global__ __launch_bounds__(256) void k_cvt_x(const float* __restrict__ src,
                                               u16* __restrict__ dst) {
  int i = (blockIdx.x * 256 + threadIdx.x) * 4;
  float4 v = *(const float4*)(src + i);
  short4v o;
  o[0] = (short)f2b(v.x); o[1] = (short)f2b(v.y);
  o[2] = (short)f2b(v.z); o[3] = (short)f2b(v.w);
  *(short4v*)(dst + i) = o;
}

// ---------- kernel 2: transpose + cvt (+optional qkv column permutation) ----------
template <int PERM>
__global__ __launch_bounds__(256) void k_tcvt(const float* __restrict__ src,
                                              u16* __restrict__ dst, int R, int C) {
  __shared__ float t[32][33];
  int bx = blockIdx.x * 32;   // col tile in src
  int by = blockIdx.y * 32;   // row tile in src
  int c = threadIdx.x & 31, r8 = threadIdx.x >> 5;
#pragma unroll
  for (int p = 0; p < 4; ++p) {
    int r = r8 + p * 8;
    t[r][c] = src[(size_t)(by + r) * C + bx + c];
  }
  __syncthreads();
#pragma unroll
  for (int p = 0; p < 4; ++p) {
    int r = r8 + p * 8;
    int co = bx + r;           // dst row before permutation = src col
    int row = co;
    float mul = 1.f;
    if (PERM) {
      int h = co / 288, rem = co - h * 288;
      int d = rem / 3, s = rem - d * 3;
      row = s * 768 + h * 96 + d;
      if (s == 0) mul = QSCALE;
    }
    dst[(size_t)row * R + by + c] = f2b(t[c][r] * mul);
  }
}

// ---------- kernel 2b: permuted (and q-scaled) qkv bias, fp32 ----------
__global__ __launch_bounds__(256) void k_permbias(const float* __restrict__ b,
                                                  float* __restrict__ bp) {
  int co = blockIdx.x * 256 + threadIdx.x;
  if (co < 2304) {
    int h = co / 288, rem = co - h * 288, d = rem / 3, s = rem - d * 3;
    bp[s * 768 + h * 96 + d] = b[co] * (s == 0 ? QSCALE : 1.f);
  }
}

// ---------- kernel 3: GEMM  C[M][Nn] = A[M][K] * Bt[Nn][K]^T + bias ----------
// MODE 0: QKV gemm. cols<1536 -> LDS-transposed bf16 store to obf[.][2304];
//         cols>=1536 -> direct store into vT[B*H*96][1024].
// MODE 1: proj gemm, f32 direct store.
template <int MODE>
__global__ __launch_bounds__(256, 2) void k_gemm_bt(
    const u16* __restrict__ A, const u16* __restrict__ Bt,
    const float* __restrict__ bias,
    u16* __restrict__ obf, u16* __restrict__ vtb, float* __restrict__ of32,
    int Nn, int Kdim) {
  __shared__ __align__(16) u16 Al[128 * 32];
  __shared__ __align__(16) u16 Bl[128 * 32];
  __shared__ __align__(16) u16 Cst[4][32 * 88];   // epilogue transpose (MODE 0)
  int m0 = blockIdx.x * 128, n0 = blockIdx.y * 128;
  int tid = threadIdx.x;
  int w = tid >> 6, l = tid & 63, lr = l >> 4, lc = l & 15;
  int wr = w >> 1, wc = w & 1;
  f32x4 acc[4][4] = {};
  int nkt = Kdim >> 5;
  for (int kt = 0; kt < nkt; ++kt) {
    __syncthreads();
#pragma unroll
    for (int i = 0; i < 2; ++i) {
      int idx = i * 256 + tid;              // 512 chunks of 16B per matrix
      int r = idx >> 2, c8 = (idx & 3) * 8;
      gl_lds16(A + (size_t)(m0 + r) * Kdim + kt * 32 + c8, &Al[idx * 8]);
      gl_lds16(Bt + (size_t)(n0 + r) * Kdim + kt * 32 + c8, &Bl[idx * 8]);
    }
    __syncthreads();
    short8 af[4];
#pragma unroll
    for (int mi = 0; mi < 4; ++mi)
      af[mi] = *(const short8*)&Al[(wr * 64 + mi * 16 + lc) * 32 + lr * 8];
#pragma unroll
    for (int ni = 0; ni < 4; ++ni) {
      short8 bf = *(const short8*)&Bl[(wc * 64 + ni * 16 + lc) * 32 + lr * 8];
#pragma unroll
      for (int mi = 0; mi < 4; ++mi)
        acc[mi][ni] = mfma16(af[mi], bf, acc[mi][ni]);
    }
  }
  acc[3][3] = fence_nops(acc[3][3]);
#pragma unroll
  for (int mi = 0; mi < 4; ++mi)
#pragma unroll
    for (int ni = 0; ni < 4; ++ni)
      if (!(mi == 3 && ni == 3)) acc[mi][ni] = fence0(acc[mi][ni]);

  if (MODE == 0) {
    if (n0 < 1536) {
      // transposed store through per-wave LDS (coalesced 16B global stores)
      u16* Cb = &Cst[w][0];
#pragma unroll
      for (int mi2 = 0; mi2 < 2; ++mi2) {
#pragma unroll
        for (int mh = 0; mh < 2; ++mh) {
          int mi = mi2 * 2 + mh;
#pragma unroll
          for (int ni = 0; ni < 4; ++ni) {
            float bv = bias[n0 + wc * 64 + ni * 16 + lc];
#pragma unroll
            for (int r = 0; r < 4; ++r)
              Cb[(mh * 16 + lr * 4 + r) * 88 + ni * 16 + lc] =
                  f2b(acc[mi][ni][r] + bv);
          }
        }
#pragma unroll
        for (int i = 0; i < 4; ++i) {
          int idx = i * 64 + l;
          int row = idx >> 3, c8 = idx & 7;
          short8 vv = *(const short8*)&Cb[row * 88 + c8 * 8];
          int grow = m0 + wr * 64 + mi2 * 32 + row;
          int gcol = n0 + wc * 64 + c8 * 8;
          *(short8*)(obf + (size_t)grow * Nn + gcol) = vv;
        }
      }
    } else {
      // V section: write directly in vT layout [(b*8+h)*96+d][1024]
#pragma unroll
      for (int mi = 0; mi < 4; ++mi) {
#pragma unroll
        for (int ni = 0; ni < 4; ++ni) {
          int col = n0 + wc * 64 + ni * 16 + lc;
          float bv = bias[col];
          int dall = col - 1536;                       // = h*96 + d
          int row0 = m0 + wr * 64 + mi * 16 + lr * 4;  // rows 4-aligned, same b
          short4v o4;
#pragma unroll
          for (int r = 0; r < 4; ++r) o4[r] = (short)f2b(acc[mi][ni][r] + bv);
          *(short4v*)(vtb + ((size_t)(row0 >> 10) * 768 + dall) * 1024 +
                      (row0 & 1023)) = o4;
        }
      }
    }
  } else {
#pragma unroll
    for (int mi = 0; mi < 4; ++mi) {
#pragma unroll
      for (int ni = 0; ni < 4; ++ni) {
        int col = n0 + wc * 64 + ni * 16 + lc;
        float bv = bias[col];
        int row0 = m0 + wr * 64 + mi * 16 + lr * 4;
#pragma unroll
        for (int r = 0; r < 4; ++r)
          of32[(size_t)(row0 + r) * Nn + col] = acc[mi][ni][r] + bv;
      }
    }
  }
}

// ---------- kernel 4: flash attention (swapped-operand, KVBLK=64) ----------
// block = (qt,h,b), b fastest (XCD L2 locality). 4 waves x 32 q rows.
// QK^T computed TRANSPOSED: S^T = K·Q^T -> each lane holds a q-row's scores
// along k in-register -> softmax reductions are in-lane + 2 shfls.
// PV computed as O^T = V^T·P^T (A-frags from vT are 16B contiguous loads).
// K double-buffered in LDS via global_load_lds; ONE barrier per kv-tile.
// LDS 43008B -> 3 blocks/CU; VGPR capped for 3 waves/SIMD.
__global__ __launch_bounds__(256, 3) void k_attn(const u16* __restrict__ qkvp,
                                                 const u16* __restrict__ vt,
                                                 u16* __restrict__ ctx) {
  __shared__ __align__(16) u16 smem[21504];   // Kb[2][64*96] | Pw[4][32*72]
  int blk = blockIdx.x;
  int b = blk & 7, h = (blk >> 3) & 7, qt = blk >> 6;
  int tid = threadIdx.x, w = tid >> 6, l = tid & 63;
  int lr = l >> 4, lc = l & 15;
  int q0 = qt * 128 + w * 32;
  const u16* qptr = qkvp + (size_t)b * 1024 * 2304 + h * 96;
  const u16* kptr = qptr + 768;
  const u16* vtp  = vt + (size_t)(b * 768 + h * 96) * 1024;
  u16* Pw = smem + 12288 + w * 2304;          // [32][72]  (P^T stored as [q][k])

  // K staging offsets (64 rows x 12 chunks of 8 u16 = 768 = 3 x 256)
  int soff[3], doff[3];
#pragma unroll
  for (int i = 0; i < 3; ++i) {
    int idx = i * 256 + tid;
    soff[i] = (idx / 12) * 2304 + (idx % 12) * 8;
    doff[i] = idx * 8;
  }

  // Q-frags (B-operand of swapped QK^T): Q[q0+16qi+lc][32kf+8lr+j]
  short8 qf[2][3];
#pragma unroll
  for (int qi = 0; qi < 2; ++qi)
#pragma unroll
    for (int kf = 0; kf < 3; ++kf)
      qf[qi][kf] = *(const short8*)(qptr + (size_t)(q0 + qi * 16 + lc) * 2304 +
                                    kf * 32 + lr * 8);

  float mrow[2] = {-INFINITY, -INFINITY}, lrow[2] = {0.f, 0.f};
  f32x4 oacc[2][6] = {};    // O^T[d=16nf+4lr+r][q=16qi+lc]

  // prologue: stage K tile 0; preload V frags for (kt0, kchunk0)
#pragma unroll
  for (int i = 0; i < 3; ++i) gl_lds16(kptr + soff[i], smem + doff[i]);
  short8 va0[6], va1[6];
#pragma unroll
  for (int nf = 0; nf < 6; ++nf)
    va0[nf] = *(const short8*)(vtp + (size_t)(nf * 16 + lc) * 1024 + lr * 8);
  __syncthreads();

  for (int kt = 0; kt < 16; ++kt) {
    const u16* Kc = smem + (kt & 1) * 6144;
    if (kt < 15) {                          // async-stage next K tile
      const u16* kg = kptr + (size_t)(kt + 1) * 64 * 2304;
      u16* db = smem + ((kt + 1) & 1) * 6144;
#pragma unroll
      for (int i = 0; i < 3; ++i) gl_lds16(kg + soff[i], db + doff[i]);
    }

    // S^T = K Q^T : sacc[qi][kfr] holds S^T[k=16kfr+4lr+r][q=16qi+lc]
    f32x4 sacc[2][4] = {};
    __builtin_amdgcn_s_setprio(1);
#pragma unroll
    for (int kfr = 0; kfr < 4; ++kfr) {
#pragma unroll
      for (int kf = 0; kf < 3; ++kf) {
        short8 kb = *(const short8*)&Kc[(kfr * 16 + lc) * 96 + kf * 32 + lr * 8];
        sacc[0][kfr] = mfma16(kb, qf[0][kf], sacc[0][kfr]);
        sacc[1][kfr] = mfma16(kb, qf[1][kf], sacc[1][kfr]);
      }
    }
    __builtin_amdgcn_s_setprio(0);
    sacc[1][3] = fence_nops(sacc[1][3]);
#pragma unroll
    for (int qi = 0; qi < 2; ++qi)
#pragma unroll
      for (int kfr = 0; kfr < 4; ++kfr)
        if (!(qi == 1 && kfr == 3)) sacc[qi][kfr] = fence0(sacc[qi][kfr]);

    // online softmax (exp2 domain, deferred max THR=8), mostly in-lane
#pragma unroll
    for (int qi = 0; qi < 2; ++qi) {
      float mx = sacc[qi][0][0];
#pragma unroll
      for (int kfr = 0; kfr < 4; ++kfr)
#pragma unroll
        for (int r = 0; r < 4; ++r)
          if (kfr | r) mx = fmaxf(mx, sacc[qi][kfr][r]);
      mx = fmaxf(mx, __shfl_xor(mx, 16));
      mx = fmaxf(mx, __shfl_xor(mx, 32));
      if (__any(mx > mrow[qi] + 8.f)) {     // wave-uniform, rare after tile 0
        float nm = fmaxf(mrow[qi], mx);
        float sc = exp2f(mrow[qi] - nm);    // 0 on first tile
        mrow[qi] = nm;
        lrow[qi] *= sc;
#pragma unroll
        for (int nf = 0; nf < 6; ++nf)
#pragma unroll
          for (int r = 0; r < 4; ++r) oacc[qi][nf][r] *= sc;
      }
      float m = mrow[qi], rs = 0.f;
#pragma unroll
      for (int kfr = 0; kfr < 4; ++kfr) {
        float p0 = exp2f(sacc[qi][kfr][0] - m);
        float p1 = exp2f(sacc[qi][kfr][1] - m);
        float p2 = exp2f(sacc[qi][kfr][2] - m);
        float p3 = exp2f(sacc[qi][kfr][3] - m);
        rs += (p0 + p1) + (p2 + p3);
        uint2v pk;
        pk[0] = cvt_pk_bf16(p0, p1);
        pk[1] = cvt_pk_bf16(p2, p3);
        *(uint2v*)&Pw[(qi * 16 + lc) * 72 + kfr * 16 + lr * 4] = pk;
      }
      rs += __shfl_xor(rs, 16);
      rs += __shfl_xor(rs, 32);
      lrow[qi] += rs;
      if (qi == 0) {                        // mid-softmax: V frags for kchunk1
#pragma unroll
        for (int nf = 0; nf < 6; ++nf)
          va1[nf] = *(const short8*)(vtp + (size_t)(nf * 16 + lc) * 1024 +
                                     kt * 64 + 32 + lr * 8);
      }
    }
    asm volatile("s_waitcnt lgkmcnt(0)" ::: "memory");   // P visible (own wave)

    // O^T += V^T P^T, kchunk 0
    short8 pb0 = *(const short8*)&Pw[lc * 72 + lr * 8];
    short8 pb1 = *(const short8*)&Pw[(16 + lc) * 72 + lr * 8];
    __builtin_amdgcn_s_setprio(1);
#pragma unroll
    for (int nf = 0; nf < 6; ++nf) {
      oacc[0][nf] = mfma16(va0[nf], pb0, oacc[0][nf]);
      oacc[1][nf] = mfma16(va0[nf], pb1, oacc[1][nf]);
    }
    __builtin_amdgcn_s_setprio(0);
    if (kt < 15) {                          // V frags for (kt+1, kchunk0)
#pragma unroll
      for (int nf = 0; nf < 6; ++nf)
        va0[nf] = *(const short8*)(vtp + (size_t)(nf * 16 + lc) * 1024 +
                                   (kt + 1) * 64 + lr * 8);
    }
    // kchunk 1
    pb0 = *(const short8*)&Pw[lc * 72 + 32 + lr * 8];
    pb1 = *(const short8*)&Pw[(16 + lc) * 72 + 32 + lr * 8];
    __builtin_amdgcn_s_setprio(1);
#pragma unroll
    for (int nf = 0; nf < 6; ++nf) {
      oacc[0][nf] = mfma16(va1[nf], pb0, oacc[0][nf]);
      oacc[1][nf] = mfma16(va1[nf], pb1, oacc[1][nf]);
    }
    __builtin_amdgcn_s_setprio(0);
    __syncthreads();   // next K tile staged (vmcnt drained); Kc reads done
  }

  oacc[1][5] = fence_nops(oacc[1][5]);
#pragma unroll
  for (int qi = 0; qi < 2; ++qi)
#pragma unroll
    for (int nf = 0; nf < 6; ++nf)
      if (!(qi == 1 && nf == 5)) oacc[qi][nf] = fence0(oacc[qi][nf]);

  // epilogue: O^T -> O via per-wave LDS transpose, coalesced 16B stores
  u16* Cw = smem + w * 3328;                // [32][104]
  float inv[2] = {1.0f / lrow[0], 1.0f / lrow[1]};
#pragma unroll
  for (int qi = 0; qi < 2; ++qi) {
#pragma unroll
    for (int nf = 0; nf < 6; ++nf) {
      uint2v pk;
      pk[0] = cvt_pk_bf16(oacc[qi][nf][0] * inv[qi], oacc[qi][nf][1] * inv[qi]);
      pk[1] = cvt_pk_bf16(oacc[qi][nf][2] * inv[qi], oacc[qi][nf][3] * inv[qi]);
      *(uint2v*)&Cw[(qi * 16 + lc) * 104 + nf * 16 + lr * 4] = pk;
    }
  }
  asm volatile("s_waitcnt lgkmcnt(0)" ::: "memory");
  int crow0 = b * 1024 + qt * 128 + w * 32;
#pragma unroll
  for (int i = 0; i < 6; ++i) {
    int idx = i * 64 + l;                   // 32 rows x 12 chunks
    int row = idx / 12, c8 = idx % 12;
    short8 vv = *(const short8*)&Cw[row * 104 + c8 * 8];
    *(short8*)(ctx + (size_t)(crow0 + row) * 768 + h * 96 + c8 * 8) = vv;
  }
}

// ---------- launch ----------
extern "C" void kernel_launch(void* const* d_in, const int* in_sizes, int n_in,
                              void* d_out, int out_size, void* d_ws, size_t ws_size,
                              hipStream_t stream) {
  const float* x     = (const float*)d_in[0];
  const float* Wqkv  = (const float*)d_in[1];
  const float* bqkv  = (const float*)d_in[2];
  const float* Wproj = (const float*)d_in[3];
  const float* bproj = (const float*)d_in[4];
  float* out = (float*)d_out;

  char* ws = (char*)d_ws;
  u16*   xb     = (u16*)(ws);                    // 12,582,912 B (reused as ctx)
  u16*   wqkvT  = (u16*)(ws + 12582912);         //  3,538,944 B
  u16*   wprojT = (u16*)(ws + 16121856);         //  1,179,648 B
  float* bqkvp  = (float*)(ws + 17301504);       //      9,216 B
  u16*   qkvp   = (u16*)(ws + 17310720);         // 37,748,736 B (q,k cols only)
  u16*   vtb    = (u16*)(ws + 55059456);         // 12,582,912 B
  u16*   ctx    = xb;                            // xb dead after QKV GEMM

  k_cvt_x<<<6144, 256, 0, stream>>>(x, xb);
  k_tcvt<1><<<dim3(K3 / 32, Emb / 32), 256, 0, stream>>>(Wqkv, wqkvT, Emb, K3);
  k_tcvt<0><<<dim3(Emb / 32, Emb / 32), 256, 0, stream>>>(Wproj, wprojT, Emb, Emb);
  k_permbias<<<9, 256, 0, stream>>>(bqkv, bqkvp);
  k_gemm_bt<0><<<dim3(Mrows / 128, K3 / 128), 256, 0, stream>>>(
      xb, wqkvT, bqkvp, qkvp, vtb, nullptr, K3, Emb);
  k_attn<<<512, 256, 0, stream>>>(qkvp, vtb, ctx);
  k_gemm_bt<1><<<dim3(Mrows / 128, Emb / 128), 256, 0, stream>>>(
      ctx, wprojT, bproj, nullptr, nullptr, out, Emb, Emb);
}

// Round 5
// 167.250 us; speedup vs baseline: 1.0044x; 1.0044x over previous
//
#include <hip/hip_runtime.h>

typedef unsigned short u16;
typedef __attribute__((ext_vector_type(8))) short short8;
typedef __attribute__((ext_vector_type(4))) short short4v;
typedef __attribute__((ext_vector_type(4))) float f32x4;
typedef __attribute__((ext_vector_type(2))) unsigned int uint2v;

#define DEV static __device__ __forceinline__

static_assert(sizeof(short8) == 16, "short8 must be 16B");

// ---------- helpers ----------
DEV u16 f2b(float f) {                       // fp32 -> bf16, round-to-nearest-even
  union { float f; unsigned u; } a; a.f = f;
  unsigned u = a.u;
  unsigned r = (u + 0x7FFFu + ((u >> 16) & 1u)) >> 16;
  return (u16)r;
}

DEV unsigned cvt_pk_bf16(float lo, float hi) {   // {bf16(lo), bf16(hi)} packed
  unsigned r;
  asm("v_cvt_pk_bf16_f32 %0, %1, %2" : "=v"(r) : "v"(lo), "v"(hi));
  return r;
}

DEV f32x4 mfma16(short8 a, short8 b, f32x4 c) {
  asm volatile("v_mfma_f32_16x16x32_bf16 %0, %1, %2, %0" : "+v"(c) : "v"(a), "v"(b));
  return c;
}
DEV f32x4 fence_nops(f32x4 c) { asm volatile("s_nop 7\n\ts_nop 7" : "+v"(c)); return c; }
DEV f32x4 fence0(f32x4 c)     { asm volatile("" : "+v"(c)); return c; }

// async global->LDS, 16B per lane; LDS dest must be wave-uniform base + lane*16
DEV void gl_lds16(const u16* g, u16* l) {
  __builtin_amdgcn_global_load_lds(
      (const __attribute__((address_space(1))) void*)g,
      (__attribute__((address_space(3))) void*)l, 16, 0, 0);
}

// ---------- problem dims ----------
constexpr int Bz = 8, Nseq = 1024, Emb = 768, Hh = 8, Dh = 96;
constexpr int Mrows = Bz * Nseq;    // 8192
constexpr int K3 = 3 * Emb;         // 2304
// 768^-0.5 * log2(e): softmax done in exp2 domain (saves a mul per S element)
constexpr float QSCALE = 0.05205982021128899f;

// ---------- kernel 1: x fp32 -> bf16 ----------
__global__ __launch_bounds__(256) void k_cvt_x(const float* __restrict__ src,
                                               u16* __restrict__ dst) {
  int i = (blockIdx.x * 256 + threadIdx.x) * 4;
  float4 v = *(const float4*)(src + i);
  short4v o;
  o[0] = (short)f2b(v.x); o[1] = (short)f2b(v.y);
  o[2] = (short)f2b(v.z); o[3] = (short)f2b(v.w);
  *(short4v*)(dst + i) = o;
}

// ---------- kernel 2: transpose + cvt (+optional qkv column permutation) ----------
template <int PERM>
__global__ __launch_bounds__(256) void k_tcvt(const float* __restrict__ src,
                                              u16* __restrict__ dst, int R, int C) {
  __shared__ float t[32][33];
  int bx = blockIdx.x * 32;   // col tile in src
  int by = blockIdx.y * 32;   // row tile in src
  int c = threadIdx.x & 31, r8 = threadIdx.x >> 5;
#pragma unroll
  for (int p = 0; p < 4; ++p) {
    int r = r8 + p * 8;
    t[r][c] = src[(size_t)(by + r) * C + bx + c];
  }
  __syncthreads();
#pragma unroll
  for (int p = 0; p < 4; ++p) {
    int r = r8 + p * 8;
    int co = bx + r;           // dst row before permutation = src col
    int row = co;
    float mul = 1.f;
    if (PERM) {
      int h = co / 288, rem = co - h * 288;
      int d = rem / 3, s = rem - d * 3;
      row = s * 768 + h * 96 + d;
      if (s == 0) mul = QSCALE;
    }
    dst[(size_t)row * R + by + c] = f2b(t[c][r] * mul);
  }
}

// ---------- kernel 2b: permuted (and q-scaled) qkv bias, fp32 ----------
__global__ __launch_bounds__(256) void k_permbias(const float* __restrict__ b,
                                                  float* __restrict__ bp) {
  int co = blockIdx.x * 256 + threadIdx.x;
  if (co < 2304) {
    int h = co / 288, rem = co - h * 288, d = rem / 3, s = rem - d * 3;
    bp[s * 768 + h * 96 + d] = b[co] * (s == 0 ? QSCALE : 1.f);
  }
}

// ---------- kernel 3: GEMM  C[M][Nn] = A[M][K] * Bt[Nn][K]^T + bias ----------
// MODE 0: QKV gemm. cols<1536 -> LDS-transposed bf16 store to obf[.][2304];
//         cols>=1536 -> direct store into vT[B*H*96][1024].
// MODE 1: proj gemm, f32 direct store.
template <int MODE>
__global__ __launch_bounds__(256, 2) void k_gemm_bt(
    const u16* __restrict__ A, const u16* __restrict__ Bt,
    const float* __restrict__ bias,
    u16* __restrict__ obf, u16* __restrict__ vtb, float* __restrict__ of32,
    int Nn, int Kdim) {
  __shared__ __align__(16) u16 Al[128 * 32];
  __shared__ __align__(16) u16 Bl[128 * 32];
  __shared__ __align__(16) u16 Cst[4][32 * 88];   // epilogue transpose (MODE 0)
  int m0 = blockIdx.x * 128, n0 = blockIdx.y * 128;
  int tid = threadIdx.x;
  int w = tid >> 6, l = tid & 63, lr = l >> 4, lc = l & 15;
  int wr = w >> 1, wc = w & 1;
  f32x4 acc[4][4] = {};
  int nkt = Kdim >> 5;
  for (int kt = 0; kt < nkt; ++kt) {
    __syncthreads();
#pragma unroll
    for (int i = 0; i < 2; ++i) {
      int idx = i * 256 + tid;              // 512 chunks of 16B per matrix
      int r = idx >> 2, c8 = (idx & 3) * 8;
      gl_lds16(A + (size_t)(m0 + r) * Kdim + kt * 32 + c8, &Al[idx * 8]);
      gl_lds16(Bt + (size_t)(n0 + r) * Kdim + kt * 32 + c8, &Bl[idx * 8]);
    }
    __syncthreads();
    short8 af[4];
#pragma unroll
    for (int mi = 0; mi < 4; ++mi)
      af[mi] = *(const short8*)&Al[(wr * 64 + mi * 16 + lc) * 32 + lr * 8];
#pragma unroll
    for (int ni = 0; ni < 4; ++ni) {
      short8 bf = *(const short8*)&Bl[(wc * 64 + ni * 16 + lc) * 32 + lr * 8];
#pragma unroll
      for (int mi = 0; mi < 4; ++mi)
        acc[mi][ni] = mfma16(af[mi], bf, acc[mi][ni]);
    }
  }
  acc[3][3] = fence_nops(acc[3][3]);
#pragma unroll
  for (int mi = 0; mi < 4; ++mi)
#pragma unroll
    for (int ni = 0; ni < 4; ++ni)
      if (!(mi == 3 && ni == 3)) acc[mi][ni] = fence0(acc[mi][ni]);

  if (MODE == 0) {
    if (n0 < 1536) {
      // transposed store through per-wave LDS (coalesced 16B global stores)
      u16* Cb = &Cst[w][0];
#pragma unroll
      for (int mi2 = 0; mi2 < 2; ++mi2) {
#pragma unroll
        for (int mh = 0; mh < 2; ++mh) {
          int mi = mi2 * 2 + mh;
#pragma unroll
          for (int ni = 0; ni < 4; ++ni) {
            float bv = bias[n0 + wc * 64 + ni * 16 + lc];
#pragma unroll
            for (int r = 0; r < 4; ++r)
              Cb[(mh * 16 + lr * 4 + r) * 88 + ni * 16 + lc] =
                  f2b(acc[mi][ni][r] + bv);
          }
        }
#pragma unroll
        for (int i = 0; i < 4; ++i) {
          int idx = i * 64 + l;
          int row = idx >> 3, c8 = idx & 7;
          short8 vv = *(const short8*)&Cb[row * 88 + c8 * 8];
          int grow = m0 + wr * 64 + mi2 * 32 + row;
          int gcol = n0 + wc * 64 + c8 * 8;
          *(short8*)(obf + (size_t)grow * Nn + gcol) = vv;
        }
      }
    } else {
      // V section: write directly in vT layout [(b*8+h)*96+d][1024]
#pragma unroll
      for (int mi = 0; mi < 4; ++mi) {
#pragma unroll
        for (int ni = 0; ni < 4; ++ni) {
          int col = n0 + wc * 64 + ni * 16 + lc;
          float bv = bias[col];
          int dall = col - 1536;                       // = h*96 + d
          int row0 = m0 + wr * 64 + mi * 16 + lr * 4;  // rows 4-aligned, same b
          short4v o4;
#pragma unroll
          for (int r = 0; r < 4; ++r) o4[r] = (short)f2b(acc[mi][ni][r] + bv);
          *(short4v*)(vtb + ((size_t)(row0 >> 10) * 768 + dall) * 1024 +
                      (row0 & 1023)) = o4;
        }
      }
    }
  } else {
#pragma unroll
    for (int mi = 0; mi < 4; ++mi) {
#pragma unroll
      for (int ni = 0; ni < 4; ++ni) {
        int col = n0 + wc * 64 + ni * 16 + lc;
        float bv = bias[col];
        int row0 = m0 + wr * 64 + mi * 16 + lr * 4;
#pragma unroll
        for (int r = 0; r < 4; ++r)
          of32[(size_t)(row0 + r) * Nn + col] = acc[mi][ni][r] + bv;
      }
    }
  }
}

// ---------- kernel 4: flash attention (swapped-operand, KVBLK=64) ----------
// block = (qt,h,b), b fastest (XCD L2 locality). 4 waves x 32 q rows.
// S^T = K·Q^T -> lane holds a q-row's scores along k in-register.
// PV as O^T = V^T·P^T. K double-buffered in LDS via global_load_lds.
// SPILL FIX vs r4: single transient V-frag buffer per chunk instead of two
// persistent ones; chunk0 loads issue BEFORE the K staging (vmcnt retires
// in order, so PV-chunk0's wait doesn't drain staging); chunk1 loads issue
// after softmax, hidden under PV-chunk0 MFMAs. Peak live ~150 VGPR < 168.
__global__ __launch_bounds__(256, 3) void k_attn(const u16* __restrict__ qkvp,
                                                 const u16* __restrict__ vt,
                                                 u16* __restrict__ ctx) {
  __shared__ __align__(16) u16 smem[21504];   // Kb[2][64*96] | Pw[4][32*72]
  int blk = blockIdx.x;
  int b = blk & 7, h = (blk >> 3) & 7, qt = blk >> 6;
  int tid = threadIdx.x, w = tid >> 6, l = tid & 63;
  int lr = l >> 4, lc = l & 15;
  int q0 = qt * 128 + w * 32;
  const u16* qptr = qkvp + (size_t)b * 1024 * 2304 + h * 96;
  const u16* kptr = qptr + 768;
  const u16* vtp  = vt + (size_t)(b * 768 + h * 96) * 1024 +
                    (size_t)lc * 1024 + lr * 8;   // per-lane V base
  u16* Pw = smem + 12288 + w * 2304;          // [32][72]  (P^T stored as [q][k])

  // K staging offsets (64 rows x 12 chunks of 8 u16 = 768 = 3 x 256)
  int soff[3], doff[3];
#pragma unroll
  for (int i = 0; i < 3; ++i) {
    int idx = i * 256 + tid;
    soff[i] = (idx / 12) * 2304 + (idx % 12) * 8;
    doff[i] = idx * 8;
  }

  // Q-frags (B-operand of swapped QK^T): Q[q0+16qi+lc][32kf+8lr+j]
  short8 qf[2][3];
#pragma unroll
  for (int qi = 0; qi < 2; ++qi)
#pragma unroll
    for (int kf = 0; kf < 3; ++kf)
      qf[qi][kf] = *(const short8*)(qptr + (size_t)(q0 + qi * 16 + lc) * 2304 +
                                    kf * 32 + lr * 8);

  float mrow[2] = {-INFINITY, -INFINITY}, lrow[2] = {0.f, 0.f};
  f32x4 oacc[2][6] = {};    // O^T[d=16nf+4lr+r][q=16qi+lc]

  // prologue: stage K tile 0
#pragma unroll
  for (int i = 0; i < 3; ++i) gl_lds16(kptr + soff[i], smem + doff[i]);
  __syncthreads();

  for (int kt = 0; kt < 16; ++kt) {
    const u16* Kc = smem + (kt & 1) * 6144;
    const u16* vkt = vtp + kt * 64;

    // V frags, kchunk 0 — issued BEFORE staging so their vmcnt wait
    // (at PV chunk0) retires without draining the staging queue.
    short8 va[6];
#pragma unroll
    for (int nf = 0; nf < 6; ++nf)
      va[nf] = *(const short8*)(vkt + (size_t)nf * 16 * 1024);

    if (kt < 15) {                          // async-stage next K tile
      const u16* kg = kptr + (size_t)(kt + 1) * 64 * 2304;
      u16* db = smem + ((kt + 1) & 1) * 6144;
#pragma unroll
      for (int i = 0; i < 3; ++i) gl_lds16(kg + soff[i], db + doff[i]);
    }

    // S^T = K Q^T : sacc[qi][kfr] holds S^T[k=16kfr+4lr+r][q=16qi+lc]
    f32x4 sacc[2][4] = {};
    __builtin_amdgcn_s_setprio(1);
#pragma unroll
    for (int kfr = 0; kfr < 4; ++kfr) {
#pragma unroll
      for (int kf = 0; kf < 3; ++kf) {
        short8 kb = *(const short8*)&Kc[(kfr * 16 + lc) * 96 + kf * 32 + lr * 8];
        sacc[0][kfr] = mfma16(kb, qf[0][kf], sacc[0][kfr]);
        sacc[1][kfr] = mfma16(kb, qf[1][kf], sacc[1][kfr]);
      }
    }
    __builtin_amdgcn_s_setprio(0);
    sacc[1][3] = fence_nops(sacc[1][3]);
#pragma unroll
    for (int qi = 0; qi < 2; ++qi)
#pragma unroll
      for (int kfr = 0; kfr < 4; ++kfr)
        if (!(qi == 1 && kfr == 3)) sacc[qi][kfr] = fence0(sacc[qi][kfr]);

    // online softmax (exp2 domain, deferred max THR=8), mostly in-lane
#pragma unroll
    for (int qi = 0; qi < 2; ++qi) {
      float mx = sacc[qi][0][0];
#pragma unroll
      for (int kfr = 0; kfr < 4; ++kfr)
#pragma unroll
        for (int r = 0; r < 4; ++r)
          if (kfr | r) mx = fmaxf(mx, sacc[qi][kfr][r]);
      mx = fmaxf(mx, __shfl_xor(mx, 16));
      mx = fmaxf(mx, __shfl_xor(mx, 32));
      if (__any(mx > mrow[qi] + 8.f)) {     // wave-uniform, rare after tile 0
        float nm = fmaxf(mrow[qi], mx);
        float sc = exp2f(mrow[qi] - nm);    // 0 on first tile
        mrow[qi] = nm;
        lrow[qi] *= sc;
#pragma unroll
        for (int nf = 0; nf < 6; ++nf)
#pragma unroll
          for (int r = 0; r < 4; ++r) oacc[qi][nf][r] *= sc;
      }
      float m = mrow[qi], rs = 0.f;
#pragma unroll
      for (int kfr = 0; kfr < 4; ++kfr) {
        float p0 = exp2f(sacc[qi][kfr][0] - m);
        float p1 = exp2f(sacc[qi][kfr][1] - m);
        float p2 = exp2f(sacc[qi][kfr][2] - m);
        float p3 = exp2f(sacc[qi][kfr][3] - m);
        rs += (p0 + p1) + (p2 + p3);
        uint2v pk;
        pk[0] = cvt_pk_bf16(p0, p1);
        pk[1] = cvt_pk_bf16(p2, p3);
        *(uint2v*)&Pw[(qi * 16 + lc) * 72 + kfr * 16 + lr * 4] = pk;
      }
      rs += __shfl_xor(rs, 16);
      rs += __shfl_xor(rs, 32);
      lrow[qi] += rs;
    }
    asm volatile("s_waitcnt lgkmcnt(0)" ::: "memory");   // P visible (own wave)

    // P frags chunk0 + V frags chunk1 (chunk1 loads hide under PV chunk0)
    short8 pb0 = *(const short8*)&Pw[lc * 72 + lr * 8];
    short8 pb1 = *(const short8*)&Pw[(16 + lc) * 72 + lr * 8];
    short8 vc[6];
#pragma unroll
    for (int nf = 0; nf < 6; ++nf)
      vc[nf] = *(const short8*)(vkt + (size_t)nf * 16 * 1024 + 32);

    // O^T += V^T P^T, kchunk 0
    __builtin_amdgcn_s_setprio(1);
#pragma unroll
    for (int nf = 0; nf < 6; ++nf) {
      oacc[0][nf] = mfma16(va[nf], pb0, oacc[0][nf]);
      oacc[1][nf] = mfma16(va[nf], pb1, oacc[1][nf]);
    }
    __builtin_amdgcn_s_setprio(0);

    // kchunk 1
    pb0 = *(const short8*)&Pw[lc * 72 + 32 + lr * 8];
    pb1 = *(const short8*)&Pw[(16 + lc) * 72 + 32 + lr * 8];
    __builtin_amdgcn_s_setprio(1);
#pragma unroll
    for (int nf = 0; nf < 6; ++nf) {
      oacc[0][nf] = mfma16(vc[nf], pb0, oacc[0][nf]);
      oacc[1][nf] = mfma16(vc[nf], pb1, oacc[1][nf]);
    }
    __builtin_amdgcn_s_setprio(0);
    __syncthreads();   // next K tile staged (vmcnt drained); Kc reads done
  }

  oacc[1][5] = fence_nops(oacc[1][5]);
#pragma unroll
  for (int qi = 0; qi < 2; ++qi)
#pragma unroll
    for (int nf = 0; nf < 6; ++nf)
      if (!(qi == 1 && nf == 5)) oacc[qi][nf] = fence0(oacc[qi][nf]);

  // epilogue: O^T -> O via per-wave LDS transpose, coalesced 16B stores
  u16* Cw = smem + w * 3328;                // [32][104]
  float inv[2] = {1.0f / lrow[0], 1.0f / lrow[1]};
#pragma unroll
  for (int qi = 0; qi < 2; ++qi) {
#pragma unroll
    for (int nf = 0; nf < 6; ++nf) {
      uint2v pk;
      pk[0] = cvt_pk_bf16(oacc[qi][nf][0] * inv[qi], oacc[qi][nf][1] * inv[qi]);
      pk[1] = cvt_pk_bf16(oacc[qi][nf][2] * inv[qi], oacc[qi][nf][3] * inv[qi]);
      *(uint2v*)&Cw[(qi * 16 + lc) * 104 + nf * 16 + lr * 4] = pk;
    }
  }
  asm volatile("s_waitcnt lgkmcnt(0)" ::: "memory");
  int crow0 = b * 1024 + qt * 128 + w * 32;
#pragma unroll
  for (int i = 0; i < 6; ++i) {
    int idx = i * 64 + l;                   // 32 rows x 12 chunks
    int row = idx / 12, c8 = idx % 12;
    short8 vv = *(const short8*)&Cw[row * 104 + c8 * 8];
    *(short8*)(ctx + (size_t)(crow0 + row) * 768 + h * 96 + c8 * 8) = vv;
  }
}

// ---------- launch ----------
extern "C" void kernel_launch(void* const* d_in, const int* in_sizes, int n_in,
                              void* d_out, int out_size, void* d_ws, size_t ws_size,
                              hipStream_t stream) {
  const float* x     = (const float*)d_in[0];
  const float* Wqkv  = (const float*)d_in[1];
  const float* bqkv  = (const float*)d_in[2];
  const float* Wproj = (const float*)d_in[3];
  const float* bproj = (const float*)d_in[4];
  float* out = (float*)d_out;

  char* ws = (char*)d_ws;
  u16*   xb     = (u16*)(ws);                    // 12,582,912 B (reused as ctx)
  u16*   wqkvT  = (u16*)(ws + 12582912);         //  3,538,944 B
  u16*   wprojT = (u16*)(ws + 16121856);         //  1,179,648 B
  float* bqkvp  = (float*)(ws + 17301504);       //      9,216 B
  u16*   qkvp   = (u16*)(ws + 17310720);         // 37,748,736 B (q,k cols only)
  u16*   vtb    = (u16*)(ws + 55059456);         // 12,582,912 B
  u16*   ctx    = xb;                            // xb dead after QKV GEMM

  k_cvt_x<<<6144, 256, 0, stream>>>(x, xb);
  k_tcvt<1><<<dim3(K3 / 32, Emb / 32), 256, 0, stream>>>(Wqkv, wqkvT, Emb, K3);
  k_tcvt<0><<<dim3(Emb / 32, Emb / 32), 256, 0, stream>>>(Wproj, wprojT, Emb, Emb);
  k_permbias<<<9, 256, 0, stream>>>(bqkv, bqkvp);
  k_gemm_bt<0><<<dim3(Mrows / 128, K3 / 128), 256, 0, stream>>>(
      xb, wqkvT, bqkvp, qkvp, vtb, nullptr, K3, Emb);
  k_attn<<<512, 256, 0, stream>>>(qkvp, vtb, ctx);
  k_gemm_bt<1><<<dim3(Mrows / 128, Emb / 128), 256, 0, stream>>>(
      ctx, wprojT, bproj, nullptr, nullptr, out, Emb, Emb);
}

// Round 6
// 148.849 us; speedup vs baseline: 1.1286x; 1.1236x over previous
//
#include <hip/hip_runtime.h>

typedef unsigned short u16;
typedef __attribute__((ext_vector_type(8))) short short8;   // 8 bf16 (guide §3 frag_ab)
typedef __attribute__((ext_vector_type(4))) short short4v;
typedef __attribute__((ext_vector_type(4))) float f32x4;    // frag_cd
typedef __attribute__((ext_vector_type(2))) unsigned int uint2v;

#define DEV static __device__ __forceinline__

static_assert(sizeof(short8) == 16, "short8 must be 16B");

// ---------- helpers ----------
DEV u16 f2b(float f) {                       // fp32 -> bf16, round-to-nearest-even
  union { float f; unsigned u; } a; a.f = f;
  unsigned u = a.u;
  unsigned r = (u + 0x7FFFu + ((u >> 16) & 1u)) >> 16;
  return (u16)r;
}

DEV unsigned cvt_pk_bf16(float lo, float hi) {   // {bf16(lo), bf16(hi)} packed
  unsigned r;
  asm("v_cvt_pk_bf16_f32 %0, %1, %2" : "=v"(r) : "v"(lo), "v"(hi));
  return r;
}

// MFMA via builtin: compiler manages hazards + can allocate accumulators on the
// AGPR side of the gfx950 unified file (inline-asm "v" constraints pinned
// everything into the arch-VGPR half -> scratch spill, r4/r5 lesson).
DEV f32x4 mfma16(short8 a, short8 b, f32x4 c) {
  return __builtin_amdgcn_mfma_f32_16x16x32_bf16(a, b, c, 0, 0, 0);
}

// async global->LDS, 16B per lane; LDS dest must be wave-uniform base + lane*16
DEV void gl_lds16(const u16* g, u16* l) {
  __builtin_amdgcn_global_load_lds(
      (const __attribute__((address_space(1))) void*)g,
      (__attribute__((address_space(3))) void*)l, 16, 0, 0);
}

// ---------- problem dims ----------
constexpr int Bz = 8, Nseq = 1024, Emb = 768, Hh = 8, Dh = 96;
constexpr int Mrows = Bz * Nseq;    // 8192
constexpr int K3 = 3 * Emb;         // 2304
// 768^-0.5 * log2(e): softmax done in exp2 domain (saves a mul per S element)
constexpr float QSCALE = 0.05205982021128899f;

// ---------- kernel 1: x fp32 -> bf16 ----------
__global__ __launch_bounds__(256) void k_cvt_x(const float* __restrict__ src,
                                               u16* __restrict__ dst) {
  int i = (blockIdx.x * 256 + threadIdx.x) * 4;
  float4 v = *(const float4*)(src + i);
  short4v o;
  o[0] = (short)f2b(v.x); o[1] = (short)f2b(v.y);
  o[2] = (short)f2b(v.z); o[3] = (short)f2b(v.w);
  *(short4v*)(dst + i) = o;
}

// ---------- kernel 2: transpose + cvt (+optional qkv column permutation) ----------
template <int PERM>
__global__ __launch_bounds__(256) void k_tcvt(const float* __restrict__ src,
                                              u16* __restrict__ dst, int R, int C) {
  __shared__ float t[32][33];
  int bx = blockIdx.x * 32;   // col tile in src
  int by = blockIdx.y * 32;   // row tile in src
  int c = threadIdx.x & 31, r8 = threadIdx.x >> 5;
#pragma unroll
  for (int p = 0; p < 4; ++p) {
    int r = r8 + p * 8;
    t[r][c] = src[(size_t)(by + r) * C + bx + c];
  }
  __syncthreads();
#pragma unroll
  for (int p = 0; p < 4; ++p) {
    int r = r8 + p * 8;
    int co = bx + r;           // dst row before permutation = src col
    int row = co;
    float mul = 1.f;
    if (PERM) {
      int h = co / 288, rem = co - h * 288;
      int d = rem / 3, s = rem - d * 3;
      row = s * 768 + h * 96 + d;
      if (s == 0) mul = QSCALE;
    }
    dst[(size_t)row * R + by + c] = f2b(t[c][r] * mul);
  }
}

// ---------- kernel 2b: permuted (and q-scaled) qkv bias, fp32 ----------
__global__ __launch_bounds__(256) void k_permbias(const float* __restrict__ b,
                                                  float* __restrict__ bp) {
  int co = blockIdx.x * 256 + threadIdx.x;
  if (co < 2304) {
    int h = co / 288, rem = co - h * 288, d = rem / 3, s = rem - d * 3;
    bp[s * 768 + h * 96 + d] = b[co] * (s == 0 ? QSCALE : 1.f);
  }
}

// ---------- kernel 3: GEMM  C[M][Nn] = A[M][K] * Bt[Nn][K]^T + bias ----------
// MODE 0: QKV gemm. cols<1536 -> LDS-transposed bf16 store to obf[.][2304];
//         cols>=1536 -> direct store into vT[B*H*96][1024].
// MODE 1: proj gemm, f32 direct store.
template <int MODE>
__global__ __launch_bounds__(256, 2) void k_gemm_bt(
    const u16* __restrict__ A, const u16* __restrict__ Bt,
    const float* __restrict__ bias,
    u16* __restrict__ obf, u16* __restrict__ vtb, float* __restrict__ of32,
    int Nn, int Kdim) {
  __shared__ __align__(16) u16 Al[128 * 32];
  __shared__ __align__(16) u16 Bl[128 * 32];
  __shared__ __align__(16) u16 Cst[4][32 * 88];   // epilogue transpose (MODE 0)
  int m0 = blockIdx.x * 128, n0 = blockIdx.y * 128;
  int tid = threadIdx.x;
  int w = tid >> 6, l = tid & 63, lr = l >> 4, lc = l & 15;
  int wr = w >> 1, wc = w & 1;
  f32x4 acc[4][4] = {};
  int nkt = Kdim >> 5;
  for (int kt = 0; kt < nkt; ++kt) {
    __syncthreads();
#pragma unroll
    for (int i = 0; i < 2; ++i) {
      int idx = i * 256 + tid;              // 512 chunks of 16B per matrix
      int r = idx >> 2, c8 = (idx & 3) * 8;
      gl_lds16(A + (size_t)(m0 + r) * Kdim + kt * 32 + c8, &Al[idx * 8]);
      gl_lds16(Bt + (size_t)(n0 + r) * Kdim + kt * 32 + c8, &Bl[idx * 8]);
    }
    __syncthreads();
    short8 af[4];
#pragma unroll
    for (int mi = 0; mi < 4; ++mi)
      af[mi] = *(const short8*)&Al[(wr * 64 + mi * 16 + lc) * 32 + lr * 8];
#pragma unroll
    for (int ni = 0; ni < 4; ++ni) {
      short8 bf = *(const short8*)&Bl[(wc * 64 + ni * 16 + lc) * 32 + lr * 8];
#pragma unroll
      for (int mi = 0; mi < 4; ++mi)
        acc[mi][ni] = mfma16(af[mi], bf, acc[mi][ni]);
    }
  }

  if (MODE == 0) {
    if (n0 < 1536) {
      // transposed store through per-wave LDS (coalesced 16B global stores)
      u16* Cb = &Cst[w][0];
#pragma unroll
      for (int mi2 = 0; mi2 < 2; ++mi2) {
#pragma unroll
        for (int mh = 0; mh < 2; ++mh) {
          int mi = mi2 * 2 + mh;
#pragma unroll
          for (int ni = 0; ni < 4; ++ni) {
            float bv = bias[n0 + wc * 64 + ni * 16 + lc];
#pragma unroll
            for (int r = 0; r < 4; ++r)
              Cb[(mh * 16 + lr * 4 + r) * 88 + ni * 16 + lc] =
                  f2b(acc[mi][ni][r] + bv);
          }
        }
#pragma unroll
        for (int i = 0; i < 4; ++i) {
          int idx = i * 64 + l;
          int row = idx >> 3, c8 = idx & 7;
          short8 vv = *(const short8*)&Cb[row * 88 + c8 * 8];
          int grow = m0 + wr * 64 + mi2 * 32 + row;
          int gcol = n0 + wc * 64 + c8 * 8;
          *(short8*)(obf + (size_t)grow * Nn + gcol) = vv;
        }
      }
    } else {
      // V section: write directly in vT layout [(b*8+h)*96+d][1024]
#pragma unroll
      for (int mi = 0; mi < 4; ++mi) {
#pragma unroll
        for (int ni = 0; ni < 4; ++ni) {
          int col = n0 + wc * 64 + ni * 16 + lc;
          float bv = bias[col];
          int dall = col - 1536;                       // = h*96 + d
          int row0 = m0 + wr * 64 + mi * 16 + lr * 4;  // rows 4-aligned, same b
          short4v o4;
#pragma unroll
          for (int r = 0; r < 4; ++r) o4[r] = (short)f2b(acc[mi][ni][r] + bv);
          *(short4v*)(vtb + ((size_t)(row0 >> 10) * 768 + dall) * 1024 +
                      (row0 & 1023)) = o4;
        }
      }
    }
  } else {
#pragma unroll
    for (int mi = 0; mi < 4; ++mi) {
#pragma unroll
      for (int ni = 0; ni < 4; ++ni) {
        int col = n0 + wc * 64 + ni * 16 + lc;
        float bv = bias[col];
        int row0 = m0 + wr * 64 + mi * 16 + lr * 4;
#pragma unroll
        for (int r = 0; r < 4; ++r)
          of32[(size_t)(row0 + r) * Nn + col] = acc[mi][ni][r] + bv;
      }
    }
  }
}

// ---------- kernel 4: flash attention (swapped-operand, KVBLK=64) ----------
// block = (qt,h,b), b fastest (XCD L2 locality). 4 waves x 32 q rows.
// S^T = K·Q^T -> lane holds a q-row's scores along k in-register.
// PV as O^T = V^T·P^T. K double-buffered in LDS via global_load_lds.
// r6: MFMA via builtin -> accumulators can live on the AGPR side of the
// unified file; no arch-VGPR scratch spill (r4/r5's 84-reg ceiling).
__global__ __launch_bounds__(256, 3) void k_attn(const u16* __restrict__ qkvp,
                                                 const u16* __restrict__ vt,
                                                 u16* __restrict__ ctx) {
  __shared__ __align__(16) u16 smem[21504];   // Kb[2][64*96] | Pw[4][32*72]
  int blk = blockIdx.x;
  int b = blk & 7, h = (blk >> 3) & 7, qt = blk >> 6;
  int tid = threadIdx.x, w = tid >> 6, l = tid & 63;
  int lr = l >> 4, lc = l & 15;
  int q0 = qt * 128 + w * 32;
  const u16* qptr = qkvp + (size_t)b * 1024 * 2304 + h * 96;
  const u16* kptr = qptr + 768;
  const u16* vtp  = vt + (size_t)(b * 768 + h * 96) * 1024 +
                    (size_t)lc * 1024 + lr * 8;   // per-lane V base
  u16* Pw = smem + 12288 + w * 2304;          // [32][72]  (P^T stored as [q][k])

  // K staging offsets (64 rows x 12 chunks of 8 u16 = 768 = 3 x 256)
  int soff[3], doff[3];
#pragma unroll
  for (int i = 0; i < 3; ++i) {
    int idx = i * 256 + tid;
    soff[i] = (idx / 12) * 2304 + (idx % 12) * 8;
    doff[i] = idx * 8;
  }

  // Q-frags (B-operand of swapped QK^T): Q[q0+16qi+lc][32kf+8lr+j]
  short8 qf[2][3];
#pragma unroll
  for (int qi = 0; qi < 2; ++qi)
#pragma unroll
    for (int kf = 0; kf < 3; ++kf)
      qf[qi][kf] = *(const short8*)(qptr + (size_t)(q0 + qi * 16 + lc) * 2304 +
                                    kf * 32 + lr * 8);

  float mrow[2] = {-INFINITY, -INFINITY}, lrow[2] = {0.f, 0.f};
  f32x4 oacc[2][6] = {};    // O^T[d=16nf+4lr+r][q=16qi+lc]

  // prologue: stage K tile 0
#pragma unroll
  for (int i = 0; i < 3; ++i) gl_lds16(kptr + soff[i], smem + doff[i]);
  __syncthreads();

  for (int kt = 0; kt < 16; ++kt) {
    const u16* Kc = smem + (kt & 1) * 6144;
    const u16* vkt = vtp + kt * 64;

    // V frags, kchunk 0 — issued BEFORE staging so their vmcnt wait
    // (at PV chunk0) retires without draining the staging queue.
    short8 va[6];
#pragma unroll
    for (int nf = 0; nf < 6; ++nf)
      va[nf] = *(const short8*)(vkt + (size_t)nf * 16 * 1024);

    if (kt < 15) {                          // async-stage next K tile
      const u16* kg = kptr + (size_t)(kt + 1) * 64 * 2304;
      u16* db = smem + ((kt + 1) & 1) * 6144;
#pragma unroll
      for (int i = 0; i < 3; ++i) gl_lds16(kg + soff[i], db + doff[i]);
    }

    // S^T = K Q^T : sacc[qi][kfr] holds S^T[k=16kfr+4lr+r][q=16qi+lc]
    f32x4 sacc[2][4] = {};
    __builtin_amdgcn_s_setprio(1);
#pragma unroll
    for (int kfr = 0; kfr < 4; ++kfr) {
#pragma unroll
      for (int kf = 0; kf < 3; ++kf) {
        short8 kb = *(const short8*)&Kc[(kfr * 16 + lc) * 96 + kf * 32 + lr * 8];
        sacc[0][kfr] = mfma16(kb, qf[0][kf], sacc[0][kfr]);
        sacc[1][kfr] = mfma16(kb, qf[1][kf], sacc[1][kfr]);
      }
    }
    __builtin_amdgcn_s_setprio(0);

    // online softmax (exp2 domain, deferred max THR=8), mostly in-lane
#pragma unroll
    for (int qi = 0; qi < 2; ++qi) {
      float mx = sacc[qi][0][0];
#pragma unroll
      for (int kfr = 0; kfr < 4; ++kfr)
#pragma unroll
        for (int r = 0; r < 4; ++r)
          if (kfr | r) mx = fmaxf(mx, sacc[qi][kfr][r]);
      mx = fmaxf(mx, __shfl_xor(mx, 16));
      mx = fmaxf(mx, __shfl_xor(mx, 32));
      if (__any(mx > mrow[qi] + 8.f)) {     // wave-uniform, rare after tile 0
        float nm = fmaxf(mrow[qi], mx);
        float sc = exp2f(mrow[qi] - nm);    // 0 on first tile
        mrow[qi] = nm;
        lrow[qi] *= sc;
#pragma unroll
        for (int nf = 0; nf < 6; ++nf)
#pragma unroll
          for (int r = 0; r < 4; ++r) oacc[qi][nf][r] *= sc;
      }
      float m = mrow[qi], rs = 0.f;
#pragma unroll
      for (int kfr = 0; kfr < 4; ++kfr) {
        float p0 = exp2f(sacc[qi][kfr][0] - m);
        float p1 = exp2f(sacc[qi][kfr][1] - m);
        float p2 = exp2f(sacc[qi][kfr][2] - m);
        float p3 = exp2f(sacc[qi][kfr][3] - m);
        rs += (p0 + p1) + (p2 + p3);
        uint2v pk;
        pk[0] = cvt_pk_bf16(p0, p1);
        pk[1] = cvt_pk_bf16(p2, p3);
        *(uint2v*)&Pw[(qi * 16 + lc) * 72 + kfr * 16 + lr * 4] = pk;
      }
      rs += __shfl_xor(rs, 16);
      rs += __shfl_xor(rs, 32);
      lrow[qi] += rs;
    }
    asm volatile("s_waitcnt lgkmcnt(0)" ::: "memory");   // P visible (own wave)

    // P frags chunk0 + V frags chunk1 (chunk1 loads hide under PV chunk0)
    short8 pb0 = *(const short8*)&Pw[lc * 72 + lr * 8];
    short8 pb1 = *(const short8*)&Pw[(16 + lc) * 72 + lr * 8];
    short8 vc[6];
#pragma unroll
    for (int nf = 0; nf < 6; ++nf)
      vc[nf] = *(const short8*)(vkt + (size_t)nf * 16 * 1024 + 32);

    // O^T += V^T P^T, kchunk 0
    __builtin_amdgcn_s_setprio(1);
#pragma unroll
    for (int nf = 0; nf < 6; ++nf) {
      oacc[0][nf] = mfma16(va[nf], pb0, oacc[0][nf]);
      oacc[1][nf] = mfma16(va[nf], pb1, oacc[1][nf]);
    }
    __builtin_amdgcn_s_setprio(0);

    // kchunk 1
    pb0 = *(const short8*)&Pw[lc * 72 + 32 + lr * 8];
    pb1 = *(const short8*)&Pw[(16 + lc) * 72 + 32 + lr * 8];
    __builtin_amdgcn_s_setprio(1);
#pragma unroll
    for (int nf = 0; nf < 6; ++nf) {
      oacc[0][nf] = mfma16(vc[nf], pb0, oacc[0][nf]);
      oacc[1][nf] = mfma16(vc[nf], pb1, oacc[1][nf]);
    }
    __builtin_amdgcn_s_setprio(0);
    __syncthreads();   // next K tile staged (vmcnt drained); Kc reads done
  }

  // epilogue: O^T -> O via per-wave LDS transpose, coalesced 16B stores
  u16* Cw = smem + w * 3328;                // [32][104]
  float inv[2] = {1.0f / lrow[0], 1.0f / lrow[1]};
#pragma unroll
  for (int qi = 0; qi < 2; ++qi) {
#pragma unroll
    for (int nf = 0; nf < 6; ++nf) {
      uint2v pk;
      pk[0] = cvt_pk_bf16(oacc[qi][nf][0] * inv[qi], oacc[qi][nf][1] * inv[qi]);
      pk[1] = cvt_pk_bf16(oacc[qi][nf][2] * inv[qi], oacc[qi][nf][3] * inv[qi]);
      *(uint2v*)&Cw[(qi * 16 + lc) * 104 + nf * 16 + lr * 4] = pk;
    }
  }
  asm volatile("s_waitcnt lgkmcnt(0)" ::: "memory");
  int crow0 = b * 1024 + qt * 128 + w * 32;
#pragma unroll
  for (int i = 0; i < 6; ++i) {
    int idx = i * 64 + l;                   // 32 rows x 12 chunks
    int row = idx / 12, c8 = idx % 12;
    short8 vv = *(const short8*)&Cw[row * 104 + c8 * 8];
    *(short8*)(ctx + (size_t)(crow0 + row) * 768 + h * 96 + c8 * 8) = vv;
  }
}

// ---------- launch ----------
extern "C" void kernel_launch(void* const* d_in, const int* in_sizes, int n_in,
                              void* d_out, int out_size, void* d_ws, size_t ws_size,
                              hipStream_t stream) {
  const float* x     = (const float*)d_in[0];
  const float* Wqkv  = (const float*)d_in[1];
  const float* bqkv  = (const float*)d_in[2];
  const float* Wproj = (const float*)d_in[3];
  const float* bproj = (const float*)d_in[4];
  float* out = (float*)d_out;

  char* ws = (char*)d_ws;
  u16*   xb     = (u16*)(ws);                    // 12,582,912 B (reused as ctx)
  u16*   wqkvT  = (u16*)(ws + 12582912);         //  3,538,944 B
  u16*   wprojT = (u16*)(ws + 16121856);         //  1,179,648 B
  float* bqkvp  = (float*)(ws + 17301504);       //      9,216 B
  u16*   qkvp   = (u16*)(ws + 17310720);         // 37,748,736 B (q,k cols only)
  u16*   vtb    = (u16*)(ws + 55059456);         // 12,582,912 B
  u16*   ctx    = xb;                            // xb dead after QKV GEMM

  k_cvt_x<<<6144, 256, 0, stream>>>(x, xb);
  k_tcvt<1><<<dim3(K3 / 32, Emb / 32), 256, 0, stream>>>(Wqkv, wqkvT, Emb, K3);
  k_tcvt<0><<<dim3(Emb / 32, Emb / 32), 256, 0, stream>>>(Wproj, wprojT, Emb, Emb);
  k_permbias<<<9, 256, 0, stream>>>(bqkv, bqkvp);
  k_gemm_bt<0><<<dim3(Mrows / 128, K3 / 128), 256, 0, stream>>>(
      xb, wqkvT, bqkvp, qkvp, vtb, nullptr, K3, Emb);
  k_attn<<<512, 256, 0, stream>>>(qkvp, vtb, ctx);
  k_gemm_bt<1><<<dim3(Mrows / 128, Emb / 128), 256, 0, stream>>>(
      ctx, wprojT, bproj, nullptr, nullptr, out, Emb, Emb);
}